// Round 1
// baseline (307.951 us; speedup 1.0000x reference)
//
#include <hip/hip_runtime.h>
#include <stdint.h>

typedef unsigned short ushort_t;
typedef __attribute__((ext_vector_type(8))) short s16x8;    // 8 x bf16 (4 VGPR)
typedef __attribute__((ext_vector_type(4))) float f32x4;
typedef __attribute__((ext_vector_type(16))) float f32x16;
typedef __attribute__((ext_vector_type(4))) unsigned int u32x4;

// ---------- helpers ----------
__device__ __forceinline__ unsigned short f2bf(float x) {
  union { float f; unsigned u; } a; a.f = x;
  unsigned r = a.u + 0x7fffu + ((a.u >> 16) & 1u);   // RNE
  return (unsigned short)(r >> 16);
}

// ---------- fp32 -> bf16 convert (vectorized) ----------
__global__ void cvt4(const float* __restrict__ s, ushort_t* __restrict__ d, int n4) {
  int idx = blockIdx.x * blockDim.x + threadIdx.x;
  if (idx >= n4) return;
  const float4 v = *(const float4*)(s + (size_t)idx * 4);
  ushort4 o;
  o.x = f2bf(v.x); o.y = f2bf(v.y); o.z = f2bf(v.z); o.w = f2bf(v.w);
  *(ushort4*)(d + (size_t)idx * 4) = o;
}

// ---------- build concatenated projection weight (1536 x 2048, bf16, zero-padded) ----------
__global__ void build_wcat(const float* __restrict__ aQ, const float* __restrict__ aK,
                           const float* __restrict__ aV, const float* __restrict__ bQ,
                           const float* __restrict__ bK, const float* __restrict__ bV,
                           ushort_t* __restrict__ W) {
  int idx = blockIdx.x * blockDim.x + threadIdx.x;
  if (idx >= 1536 * 2048) return;
  int row = idx >> 11, col = idx & 2047;
  float v = 0.f;
  if (row < 96)        v = aQ[row * 2048 + col];
  else if (row < 128)  v = aK[(row - 96) * 2048 + col];
  else if (row < 160)  v = aV[(row - 128) * 2048 + col];
  else if (row < 928)  v = bQ[(row - 160) * 2048 + col];
  else if (row < 1184) v = bK[(row - 928) * 2048 + col];
  else if (row < 1440) v = bV[(row - 1184) * 2048 + col];
  W[idx] = f2bf(v);
}

// ---------- GEMM: C(MxN fp32) = A(MxK bf16) * B(NxK bf16)^T ----------
// 128x128 tile, BK=64, 4 waves (each 64x64), 16x16x32 bf16 MFMA.
// LDS layout: 16B chunks, chunk = row*8 + ((col>>3) ^ (row&7))  (XOR swizzle, conflict-free reads)
__global__ __launch_bounds__(256, 2) void gemm_bt(
    const ushort_t* __restrict__ A, const ushort_t* __restrict__ B,
    float* __restrict__ C, int M, int N, int K, int NT) {
  __shared__ ushort_t Asm[128 * 64];
  __shared__ ushort_t Bsm[128 * 64];
  const int bid = blockIdx.x;
  const int mt = bid / NT, nt = bid % NT;
  const int tid = threadIdx.x;
  const int lane = tid & 63;
  const int w = tid >> 6, wr = w >> 1, wc = w & 1;

  f32x4 acc[4][4];
#pragma unroll
  for (int a1 = 0; a1 < 4; ++a1)
#pragma unroll
    for (int b1 = 0; b1 < 4; ++b1)
#pragma unroll
      for (int e = 0; e < 4; ++e) acc[a1][b1][e] = 0.f;

  const int nkt = K >> 6;
  u32x4 ra[4], rb[4];

  auto LOADT = [&](int kt) {
#pragma unroll
    for (int i = 0; i < 4; ++i) {
      int c = i * 256 + tid;          // chunk 0..1023
      int row = c >> 3;
      int scc = (c & 7) ^ (row & 7);  // pre-swizzled source column chunk
      ra[i] = *(const u32x4*)(A + (size_t)(mt * 128 + row) * K + kt * 64 + scc * 8);
      rb[i] = *(const u32x4*)(B + (size_t)(nt * 128 + row) * K + kt * 64 + scc * 8);
    }
  };

  LOADT(0);
  for (int kt = 0; kt < nkt; ++kt) {
    __syncthreads();
#pragma unroll
    for (int i = 0; i < 4; ++i) {
      int c = i * 256 + tid;
      *(u32x4*)&Asm[c * 8] = ra[i];
      *(u32x4*)&Bsm[c * 8] = rb[i];
    }
    __syncthreads();
    if (kt + 1 < nkt) LOADT(kt + 1);   // overlap next-tile loads with compute
#pragma unroll
    for (int ks = 0; ks < 2; ++ks) {
      s16x8 af[4], bfv[4];
#pragma unroll
      for (int mi = 0; mi < 4; ++mi) {
        int row = wr * 64 + mi * 16 + (lane & 15);
        int colc = ks * 4 + (lane >> 4);
        int chunk = row * 8 + (colc ^ (row & 7));
        af[mi] = *(const s16x8*)&Asm[chunk * 8];
      }
#pragma unroll
      for (int ni = 0; ni < 4; ++ni) {
        int row = wc * 64 + ni * 16 + (lane & 15);
        int colc = ks * 4 + (lane >> 4);
        int chunk = row * 8 + (colc ^ (row & 7));
        bfv[ni] = *(const s16x8*)&Bsm[chunk * 8];
      }
#pragma unroll
      for (int mi = 0; mi < 4; ++mi)
#pragma unroll
        for (int ni = 0; ni < 4; ++ni)
          acc[mi][ni] = __builtin_amdgcn_mfma_f32_16x16x32_bf16(af[mi], bfv[ni], acc[mi][ni], 0, 0, 0);
    }
  }
  // epilogue: C/D layout col=lane&15, row=(lane>>4)*4+reg (verified m89/m91)
#pragma unroll
  for (int mi = 0; mi < 4; ++mi) {
    int row0 = mt * 128 + wr * 64 + mi * 16 + ((lane >> 4) << 2);
#pragma unroll
    for (int ni = 0; ni < 4; ++ni) {
      int col = nt * 128 + wc * 64 + ni * 16 + (lane & 15);
#pragma unroll
      for (int e = 0; e < 4; ++e)
        C[(size_t)(row0 + e) * N + col] = acc[mi][ni][e];
    }
  }
}

// ---------- fuse: RoPE + rank contraction + RMSNorm -> q,k,v (B,H,T,D) bf16 ----------
__global__ __launch_bounds__(256) void fuse_qkv(
    const float* __restrict__ Cp, const float* __restrict__ cosT, const float* __restrict__ sinT,
    ushort_t* __restrict__ qb, ushort_t* __restrict__ kb, ushort_t* __restrict__ vb) {
  const int tok = blockIdx.x;             // 0..4095
  const int b = tok >> 11, t = tok & 2047;
  const float* __restrict__ row = Cp + (size_t)tok * 1536;
  __shared__ float aq[96], ak[32], av[32];
  __shared__ float rbq[768], rbk[256], bvs[256];
  __shared__ float cs[64], sn[64];
  const int tid = threadIdx.x;
  if (tid < 96)        aq[tid] = row[tid];
  else if (tid < 128)  ak[tid - 96] = row[tid];
  else if (tid < 160)  av[tid - 128] = row[tid];
  else if (tid < 224) { cs[tid - 160] = cosT[t * 64 + tid - 160];
                        sn[tid - 160] = sinT[t * 64 + tid - 160]; }
  __syncthreads();
  for (int p = tid; p < 384; p += 256) {      // rope b_q
    int r = p >> 6, d = p & 63;
    float x1 = row[160 + r * 128 + d], x2 = row[160 + r * 128 + 64 + d];
    rbq[r * 128 + d]      = x1 * cs[d] + x2 * sn[d];
    rbq[r * 128 + 64 + d] = x2 * cs[d] - x1 * sn[d];
  }
  if (tid < 128) {                            // rope b_k
    int r = tid >> 6, d = tid & 63;
    float x1 = row[928 + r * 128 + d], x2 = row[928 + r * 128 + 64 + d];
    rbk[r * 128 + d]      = x1 * cs[d] + x2 * sn[d];
    rbk[r * 128 + 64 + d] = x2 * cs[d] - x1 * sn[d];
  } else {                                    // copy b_v
    int p = tid - 128;
    bvs[p] = row[1184 + p];
    bvs[p + 128] = row[1184 + 128 + p];
  }
  __syncthreads();
  const int w = tid >> 6, lane = tid & 63;
#pragma unroll
  for (int j = 0; j < 4; ++j) {               // q: 4 heads per wave
    int h = w + 4 * j;
    float q0 = 0.f, q1 = 0.f;
#pragma unroll
    for (int r = 0; r < 6; ++r) {
      float a = aq[r * 16 + h];
      q0 += a * rbq[r * 128 + lane];
      q1 += a * rbq[r * 128 + 64 + lane];
    }
    q0 *= (1.f / 6.f); q1 *= (1.f / 6.f);
    float ss = q0 * q0 + q1 * q1;
#pragma unroll
    for (int o = 32; o; o >>= 1) ss += __shfl_xor(ss, o);
    float rms = rsqrtf(ss * (1.f / 128.f) + 1.1920929e-7f);
    size_t base = ((size_t)(b * 16 + h) * 2048 + t) * 128;
    qb[base + lane]      = f2bf(q0 * rms);
    qb[base + 64 + lane] = f2bf(q1 * rms);
  }
#pragma unroll
  for (int j = 0; j < 4; ++j) {               // k (norm) and v (no norm)
    int h = w + 4 * j;
    float k0 = ak[h] * rbk[lane]      + ak[16 + h] * rbk[128 + lane];
    float k1 = ak[h] * rbk[64 + lane] + ak[16 + h] * rbk[192 + lane];
    k0 *= 0.5f; k1 *= 0.5f;
    float ss = k0 * k0 + k1 * k1;
#pragma unroll
    for (int o = 32; o; o >>= 1) ss += __shfl_xor(ss, o);
    float rms = rsqrtf(ss * (1.f / 128.f) + 1.1920929e-7f);
    size_t base = ((size_t)(b * 16 + h) * 2048 + t) * 128;
    kb[base + lane]      = f2bf(k0 * rms);
    kb[base + 64 + lane] = f2bf(k1 * rms);
    float v0 = 0.5f * (av[h] * bvs[lane]      + av[16 + h] * bvs[128 + lane]);
    float v1 = 0.5f * (av[h] * bvs[64 + lane] + av[16 + h] * bvs[192 + lane]);
    vb[base + lane]      = f2bf(v0);
    vb[base + 64 + lane] = f2bf(v1);
  }
}

// ---------- causal flash attention, 4 waves x 32 q-rows, 32x32x16 MFMA ----------
// S^T = mfma(K, Q): col(lane&31) = q-row -> softmax is lane-local + one shfl_xor(32).
// Fixed max=0 softmax is safe: |score| <= sqrt(D) = 11.31 after rmsnorm.
__global__ __launch_bounds__(256, 2) void attn(
    const ushort_t* __restrict__ Q, const ushort_t* __restrict__ Kt,
    const ushort_t* __restrict__ Vt, ushort_t* __restrict__ Y) {
  const int qt = (int)gridDim.x - 1 - (int)blockIdx.x;   // heavy tiles first
  const int bh = blockIdx.y;
  const int b = bh >> 4, h = bh & 15;
  const int tid = threadIdx.x, lane = tid & 63, w = tid >> 6;
  const int hi = lane >> 5, li = lane & 31;
  const size_t hbase = (size_t)bh * (2048 * 128);
  const int wq0 = qt * 128 + w * 32;
  const int i = wq0 + li;                                // this lane's q-row

  s16x8 qf[8];
  const ushort_t* qrow = Q + hbase + (size_t)i * 128 + hi * 8;
#pragma unroll
  for (int c = 0; c < 8; ++c) qf[c] = *(const s16x8*)(qrow + c * 16);

  __shared__ ushort_t VT[128 * 40];                      // V^T [d][kv], stride 40 halfwords
  f32x16 o[4];
#pragma unroll
  for (int dt = 0; dt < 4; ++dt)
#pragma unroll
    for (int e = 0; e < 16; ++e) o[dt][e] = 0.f;
  float ssum = 0.f;
  const int nkv = qt * 128 + 128;
  const float scale = 0.08838834764831845f;              // 1/sqrt(128)

  for (int kv0 = 0; kv0 < nkv; kv0 += 32) {
    {                                                    // stage V^T cooperatively
      int d = tid & 127, half2 = tid >> 7;
      const ushort_t* vr = Vt + hbase + (size_t)(kv0 + half2 * 16) * 128 + d;
      ushort_t tmp[16];
#pragma unroll
      for (int j2 = 0; j2 < 16; ++j2) tmp[j2] = vr[j2 * 128];
      *(u32x4*)&VT[d * 40 + half2 * 16]     = *(const u32x4*)&tmp[0];
      *(u32x4*)&VT[d * 40 + half2 * 16 + 8] = *(const u32x4*)&tmp[8];
    }
    __syncthreads();
    if (kv0 <= wq0) {
      const ushort_t* krow = Kt + hbase + (size_t)(kv0 + li) * 128 + hi * 8;
      f32x16 st;
#pragma unroll
      for (int e = 0; e < 16; ++e) st[e] = 0.f;
#pragma unroll
      for (int c = 0; c < 8; ++c) {
        s16x8 kf = *(const s16x8*)(krow + c * 16);
        st = __builtin_amdgcn_mfma_f32_32x32x16_bf16(kf, qf[c], st, 0, 0, 0);
      }
      float p[16]; float ls = 0.f;
      const bool diag = (kv0 == wq0);
#pragma unroll
      for (int r = 0; r < 16; ++r) {
        int jrow = kv0 + (r & 3) + 8 * (r >> 2) + 4 * hi;  // kv index (C/D row map, m74/m101)
        float pv = __expf(st[r] * scale);
        if (diag && jrow > i) pv = 0.f;
        p[r] = pv; ls += pv;
      }
      ls += __shfl_xor(ls, 32);
      ssum += ls;
      unsigned xp[8], xw[8];
#pragma unroll
      for (int q2 = 0; q2 < 8; ++q2)
        xp[q2] = (unsigned)f2bf(p[2 * q2]) | ((unsigned)f2bf(p[2 * q2 + 1]) << 16);
#pragma unroll
      for (int q2 = 0; q2 < 8; ++q2)
        xw[q2] = (unsigned)__shfl_xor((int)xp[q2], 32);
#pragma unroll
      for (int c2 = 0; c2 < 2; ++c2) {                  // build P A-frag in-register
        union { s16x8 v; unsigned u[4]; } pu;
        if (hi == 0) { pu.u[0] = xp[4 * c2];     pu.u[1] = xp[4 * c2 + 1];
                       pu.u[2] = xw[4 * c2];     pu.u[3] = xw[4 * c2 + 1]; }
        else         { pu.u[0] = xw[4 * c2 + 2]; pu.u[1] = xw[4 * c2 + 3];
                       pu.u[2] = xp[4 * c2 + 2]; pu.u[3] = xp[4 * c2 + 3]; }
#pragma unroll
        for (int dt = 0; dt < 4; ++dt) {
          s16x8 vf = *(const s16x8*)&VT[(dt * 32 + li) * 40 + c2 * 16 + hi * 8];
          o[dt] = __builtin_amdgcn_mfma_f32_32x32x16_bf16(pu.v, vf, o[dt], 0, 0, 0);
        }
      }
    }
    __syncthreads();
  }
#pragma unroll
  for (int r = 0; r < 16; ++r) {
    int rr = (r & 3) + 8 * (r >> 2) + 4 * hi;
    float rs = __shfl(ssum, rr);                        // lane rr owns row rr's sum
    float inv = 1.f / rs;
    size_t yrow = (size_t)(b * 2048 + wq0 + rr);
#pragma unroll
    for (int dt = 0; dt < 4; ++dt)
      Y[yrow * 2048 + h * 128 + dt * 32 + li] = f2bf(o[dt][r] * inv);
  }
}

// ---------- launch ----------
extern "C" void kernel_launch(void* const* d_in, const int* in_sizes, int n_in,
                              void* d_out, int out_size, void* d_ws, size_t ws_size,
                              hipStream_t stream) {
  const float* x    = (const float*)d_in[0];
  const float* cosT = (const float*)d_in[1];
  const float* sinT = (const float*)d_in[2];
  const float* W_aQ = (const float*)d_in[3];
  const float* W_bQ = (const float*)d_in[4];
  const float* W_aK = (const float*)d_in[5];
  const float* W_bK = (const float*)d_in[6];
  const float* W_aV = (const float*)d_in[7];
  const float* W_bV = (const float*)d_in[8];
  const float* W_c  = (const float*)d_in[9];
  float* out = (float*)d_out;

  char* ws = (char*)d_ws;
  ushort_t* xb   = (ushort_t*)(ws);                        // 16,777,216 B (reused as ybuf)
  ushort_t* Wcat = (ushort_t*)(ws + 16777216);             //  6,291,456
  ushort_t* Wcb  = (ushort_t*)(ws + 23068672);             //  8,388,608
  float*    Cp   = (float*)   (ws + 31457280);             // 25,165,824
  ushort_t* qb   = (ushort_t*)(ws + 56623104);             // 16,777,216
  ushort_t* kb   = (ushort_t*)(ws + 73400320);             // 16,777,216
  ushort_t* vb   = (ushort_t*)(ws + 90177536);             // 16,777,216  (end ~102 MB)
  ushort_t* yb   = xb;                                     // alias: x dead after proj GEMM

  cvt4<<<8192, 256, 0, stream>>>(x, xb, 2097152);                       // x -> bf16
  build_wcat<<<12288, 256, 0, stream>>>(W_aQ, W_aK, W_aV, W_bQ, W_bK, W_bV, Wcat);
  cvt4<<<4096, 256, 0, stream>>>(W_c, Wcb, 1048576);                    // W_cproj -> bf16

  gemm_bt<<<384, 256, 0, stream>>>(xb, Wcat, Cp, 4096, 1536, 2048, 12); // projections
  fuse_qkv<<<4096, 256, 0, stream>>>(Cp, cosT, sinT, qb, kb, vb);       // rope+contract+norm
  attn<<<dim3(16, 32), 256, 0, stream>>>(qb, kb, vb, yb);               // causal attention
  gemm_bt<<<512, 256, 0, stream>>>(yb, Wcb, out, 4096, 2048, 2048, 16); // output projection
}